// Round 18
// baseline (628.310 us; speedup 1.0000x reference)
//
#include <hip/hip_runtime.h>

// Spiking self-attention block (spikformer SSA), MI355X fp32 implementation.
// T=4 B=32 C=384 H=W=14 (N=196), heads=8, d=48.
//
// Exactness: LIF spikes are EXACTLY 0/1; attention is exact integer math.
// Conv GEMM: single fp32 accumulator per output, ascending K, fmaf per step
// (matched XLA bit-for-bit rounds 1-17). MFMA dead: any reorder flips spikes.
//
// R18: LIF fused into GEMM epilogues. Column remap: block's 128 cols =
// 32 (b,n) positions x 4 t, t-fastest (cc = u*4+t; 6272/32 = 196 tiles,
// same grid). Each thread's acc[8][8] = 8 co x (2 u x 4 t) -> BN+LIF runs
// in-register in the epilogue (same __f*_rn sequence as k_mask/lif4).
// qkv kernel emits spike BYTES (29 MB vs 115 MB fp32 preacts); wp kernel
// emits the final output directly. k_mask and lif4 deleted -> 3 dispatches.
// k_attn builds masks from bytes (coalesced 64B reads + ballot).
// Compute loop / tile / register-prefetch cadence = R9 verbatim (the only
// GEMM shape that survived 7 falsifications). Staging writes become 8x b32
// (4-way conflict, staging-only). All per-output chains identical.

#define T_ 4
#define B_ 32
#define C_ 384
#define N_ 196
#define NH_ 8
#define D_ 48
#define TB_ (T_ * B_)                 // 128
#define CN_ ((size_t)C_ * N_)         // 75264
#define TBCN_ ((size_t)T_ * B_ * C_ * N_)  // 9,633,792 elements
typedef unsigned long long u64;

// ---------------------------------------------------------------------------
// GEMM + fused BN/LIF epilogue.
// Y[g][t*B+b][co][n] = sum_c Wg[co][c] * X[t*B+b][c][n], then per (co,b,n):
// LIF scan over t (th=1.0) in-register. BYTE_OUT: spike bytes to SB
// (layout [g][t][b][c][n]); else final fp32 spikes to FO ([t][b][c][n]).
// Cols: position p = b*196+n; block covers p0..p0+31 x 4 t (cc = u*4+t).
// Block: 128co x 128cc, 256 thr, 8x8/thread. BK=16 + register prefetch.
// grid: (196, 3, g).
// ---------------------------------------------------------------------------
template <bool BYTE_OUT>
__global__ __launch_bounds__(256) void gemm_lif(
    const float* __restrict__ X, const float* __restrict__ W0,
    const float* __restrict__ W1, const float* __restrict__ W2,
    const float* __restrict__ s0, const float* __restrict__ b0_,
    const float* __restrict__ s1, const float* __restrict__ b1_,
    const float* __restrict__ s2, const float* __restrict__ b2_,
    unsigned char* __restrict__ SB, float* __restrict__ FO)
{
  const int g = blockIdx.z;
  const float* __restrict__ W  = (g == 0) ? W0 : (g == 1) ? W1 : W2;
  const float* __restrict__ SC = (g == 0) ? s0 : (g == 1) ? s1 : s2;
  const float* __restrict__ BI = (g == 0) ? b0_ : (g == 1) ? b1_ : b2_;
  const int co0 = blockIdx.y * 128;
  const int p0 = blockIdx.x * 32;
  __shared__ float As[16][128];
  __shared__ float Bs[16][128];
  const int tid = threadIdx.x;
  const int tx = tid & 15, ty = tid >> 4;

  // B staging: col-thread ct = tid&31 -> (t = ct&3, u-quad uq = ct>>2);
  // k rows bk and bk+8. p-quad p0+4uq never straddles b (p0%4==0, 196%4==0).
  const int ct = tid & 31;
  const int bt = ct & 3;
  const int uq = ct >> 2;
  const int bk = tid >> 5;
  const int pq = p0 + uq * 4;
  const int bb = pq / N_;
  const int nn = pq - bb * N_;
  const float* xb = X + (size_t)(bt * B_ + bb) * CN_ + nn;
  // A staging (R9): row arow, 8 floats at ac8, scattered (transpose).
  const int arow = tid >> 1;
  const int ac8 = (tid & 1) * 8;
  const float* wrow0 = W + (size_t)(co0 + arow) * C_ + ac8;

  // Prefetch tile 0 into registers.
  float4 pa0 = *(const float4*)(wrow0);
  float4 pa1 = *(const float4*)(wrow0 + 4);
  float4 pb0 = *(const float4*)(xb + (size_t)bk * N_);
  float4 pb1 = *(const float4*)(xb + (size_t)(bk + 8) * N_);

  float acc[8][8] = {};
  for (int c0 = 0; c0 < C_; c0 += 16) {
    __syncthreads();   // prev-iter readers done (no-op on first iter)
    As[ac8 + 0][arow] = pa0.x; As[ac8 + 1][arow] = pa0.y;
    As[ac8 + 2][arow] = pa0.z; As[ac8 + 3][arow] = pa0.w;
    As[ac8 + 4][arow] = pa1.x; As[ac8 + 5][arow] = pa1.y;
    As[ac8 + 6][arow] = pa1.z; As[ac8 + 7][arow] = pa1.w;
    // cc = (4uq+i)*4 + bt = 16uq + 4i + bt  (t-fastest interleave)
    Bs[bk][16 * uq + 0 + bt] = pb0.x;
    Bs[bk][16 * uq + 4 + bt] = pb0.y;
    Bs[bk][16 * uq + 8 + bt] = pb0.z;
    Bs[bk][16 * uq + 12 + bt] = pb0.w;
    Bs[bk + 8][16 * uq + 0 + bt] = pb1.x;
    Bs[bk + 8][16 * uq + 4 + bt] = pb1.y;
    Bs[bk + 8][16 * uq + 8 + bt] = pb1.z;
    Bs[bk + 8][16 * uq + 12 + bt] = pb1.w;
    __syncthreads();
    if (c0 + 16 < C_) {  // prefetch next tile; latency hidden by compute
      pa0 = *(const float4*)(wrow0 + c0 + 16);
      pa1 = *(const float4*)(wrow0 + c0 + 20);
      pb0 = *(const float4*)(xb + (size_t)(c0 + 16 + bk) * N_);
      pb1 = *(const float4*)(xb + (size_t)(c0 + 24 + bk) * N_);
    }
#pragma unroll
    for (int k = 0; k < 16; ++k) {
      float a[8], b[8];
      *(float4*)&a[0] = *(const float4*)&As[k][ty * 4];
      *(float4*)&a[4] = *(const float4*)&As[k][64 + ty * 4];
      *(float4*)&b[0] = *(const float4*)&Bs[k][tx * 4];        // u=tx, t=0..3
      *(float4*)&b[4] = *(const float4*)&Bs[k][64 + tx * 4];   // u=16+tx
#pragma unroll
      for (int i = 0; i < 8; ++i)
#pragma unroll
        for (int j = 0; j < 8; ++j)
          acc[i][j] = fmaf(a[i], b[j], acc[i][j]);
    }
  }
  // Epilogue: BN + LIF over t per (co, position), write spikes.
  int bArr[2], nArr[2];
#pragma unroll
  for (int ug = 0; ug < 2; ++ug) {
    const int p = p0 + ug * 16 + tx;
    bArr[ug] = p / N_;
    nArr[ug] = p - bArr[ug] * N_;
  }
#pragma unroll
  for (int rg = 0; rg < 2; ++rg) {
#pragma unroll
    for (int i = 0; i < 4; ++i) {
      const int r = rg * 4 + i;
      const int co = co0 + rg * 64 + ty * 4 + i;
      const float sc = SC[co];
      const float bi = BI[co];
#pragma unroll
      for (int ug = 0; ug < 2; ++ug) {
        const int b2 = bArr[ug], n2 = nArr[ug];
        float v = 0.f;
#pragma unroll
        for (int t = 0; t < T_; ++t) {
          const float y = acc[r][ug * 4 + t];
          const float yb = __fadd_rn(__fmul_rn(y, sc), bi);
          v = __fadd_rn(v, __fmul_rn(__fsub_rn(yb, v), 0.5f));
          const bool fire = (v >= 1.0f);
          const size_t off =
              ((size_t)((g * T_ + t) * B_ + b2) * C_ + co) * N_ + n2;
          if (BYTE_OUT) SB[off] = fire ? (unsigned char)1 : (unsigned char)0;
          else          FO[off] = fire ? 1.0f : 0.0f;
          if (fire) v = 0.f;
        }
      }
    }
  }
}

// ---------------------------------------------------------------------------
// k_attn: per (h,b). Phase A: build msk[g][t][j][w] from spike bytes
// (wave-task = (g,j); 16 byte-loads in flight; ballot). Then qT + Gp
// bit-planes + apply + attn-LIF (th=0.5) + write binary fp32 spikes to O.
// ---------------------------------------------------------------------------
__global__ __launch_bounds__(1024) void k_attn(
    const unsigned char* __restrict__ S, float* __restrict__ O)
{
  const int h = blockIdx.x;   // 8
  const int b = blockIdx.y;   // 32
  __shared__ u64 msk[3][T_][D_][4];   // 18432 B
  __shared__ u64 qT[T_][208];         // 6656 B
  __shared__ u64 Gp[T_][8][D_];       // 12288 B
  const int tid = threadIdx.x;
  const int wave = tid >> 6, lane = tid & 63;

  // Phase A: bytes -> bitmasks. 144 wave-tasks (g,j) over 16 waves.
  for (int task = wave; task < 3 * D_; task += 16) {
    const int g = task / D_;
    const int j = task - g * D_;
    const int c = h * D_ + j;
    unsigned char yb[T_][4];
    bool act[4];
#pragma unroll
    for (int w = 0; w < 4; ++w) {
      const int m = w * 64 + lane;
      act[w] = (m < N_);
      const int mc = act[w] ? m : (N_ - 1);
#pragma unroll
      for (int t = 0; t < T_; ++t)
        yb[t][w] = S[((size_t)((g * T_ + t) * B_ + b) * C_ + c) * N_ + mc];
    }
#pragma unroll
    for (int t = 0; t < T_; ++t)
#pragma unroll
      for (int w = 0; w < 4; ++w) {
        const u64 bl = __ballot(act[w] && (yb[t][w] != 0));
        if (lane == 0) msk[g][t][j][w] = bl;
      }
  }
  __syncthreads();

  // qT[t][n] = q bits over j
  {
    const int t = wave >> 2, w = wave & 3;
    const int n = w * 64 + lane;
    u64 qr = 0ull;
#pragma unroll 8
    for (int j = 0; j < D_; ++j)
      qr |= ((msk[0][t][j][w] >> lane) & 1ull) << j;
    if (n < N_) qT[t][n] = qr;
  }
  // Gp[t][p][d]: bit-planes of G[j][d] = popcount_m(k_j & v_d), lanes=j
  for (int task = wave; task < T_ * D_; task += 16) {
    const int t = task / D_, d = task - (task / D_) * D_;
    const bool ja = (lane < D_);
    const int j = ja ? lane : (D_ - 1);
    const u64* kj = msk[1][t][j];
    const u64* vd = msk[2][t][d];
    const int gi = __popcll(kj[0] & vd[0]) + __popcll(kj[1] & vd[1]) +
                   __popcll(kj[2] & vd[2]) + __popcll(kj[3] & vd[3]);
#pragma unroll
    for (int p = 0; p < 8; ++p) {
      const u64 bl = __ballot(ja && ((gi >> p) & 1));
      if (lane == 0) Gp[t][p][d] = bl;
    }
  }
  __syncthreads();

  const int u = tid;
  if (u < 4 * N_) {
    const int dq = u / N_;
    const int n = u - dq * N_;
    const int d0 = dq * 12;
    float vmem[12];
#pragma unroll
    for (int i = 0; i < 12; ++i) vmem[i] = 0.f;
    for (int t = 0; t < T_; ++t) {
      const u64 qr = qT[t][n];
      float* ob = O + ((size_t)(t * B_ + b) * C_ + h * D_ + d0) * N_ + n;
#pragma unroll
      for (int i = 0; i < 12; ++i) {
        int acc = 0;
#pragma unroll
        for (int p = 0; p < 8; ++p)
          acc += __popcll(qr & Gp[t][p][d0 + i]) << p;
        const float y = __int2float_rn(acc) * 0.125f;  // exact
        vmem[i] = __fadd_rn(vmem[i], __fmul_rn(__fsub_rn(y, vmem[i]), 0.5f));
        const bool fire = (vmem[i] >= 0.5f);
        ob[(size_t)i * N_] = fire ? 1.0f : 0.0f;
        if (fire) vmem[i] = 0.f;
      }
    }
  }
}

// ---------------------------------------------------------------------------
extern "C" void kernel_launch(void* const* d_in, const int* in_sizes, int n_in,
                              void* d_out, int out_size, void* d_ws, size_t ws_size,
                              hipStream_t stream) {
  const float* x  = (const float*)d_in[0];
  const float* wq = (const float*)d_in[1];
  const float* sq = (const float*)d_in[2];
  const float* bq = (const float*)d_in[3];
  const float* wk = (const float*)d_in[4];
  const float* sk = (const float*)d_in[5];
  const float* bk = (const float*)d_in[6];
  const float* wv = (const float*)d_in[7];
  const float* sv = (const float*)d_in[8];
  const float* bv = (const float*)d_in[9];
  const float* wp = (const float*)d_in[10];
  const float* sp = (const float*)d_in[11];
  const float* bp = (const float*)d_in[12];
  float* out = (float*)d_out;

  unsigned char* S = (unsigned char*)d_ws;   // 3*TBCN bytes = 28.9 MB spikes
  float* O = (float*)(S + 3 * TBCN_);        // TBCN fp32 attn spikes

  // 1) qkv conv + BN + LIF -> spike bytes (3 dispatz in one, z = g)
  gemm_lif<true><<<dim3(196, 3, 3), 256, 0, stream>>>(
      x, wq, wk, wv, sq, bq, sk, bk, sv, bv, S, nullptr);
  // 2) attention (masks from bytes) + attn-LIF -> O fp32 spikes
  k_attn<<<dim3(NH_, B_), 1024, 0, stream>>>(S, O);
  // 3) final conv + BN + LIF -> d_out
  gemm_lif<false><<<dim3(196, 3, 1), 256, 0, stream>>>(
      O, wp, wp, wp, sp, bp, sp, bp, sp, bp, nullptr, out);
}